// Round 3
// baseline (465.005 us; speedup 1.0000x reference)
//
#include <hip/hip_runtime.h>
#include <stdint.h>

#define BATCH 1024
#define IN    256
#define HID   512
#define OUT   2

// Flat-index offset of batch (b+512) within each eps tensor (row-major):
#define HALF_W1 67108864u   // 512*HID*IN
#define HALF_B1 262144u     // 512*HID
#define HALF_W2 524288u     // 512*OUT*HID
#define HALF_B2 1024u       // 512*OUT

// ---------------- threefry2x32 (bit-exact vs JAX) ---------------------------
__host__ __device__ __forceinline__ uint32_t rotl32(uint32_t x, int r) {
    return (x << r) | (x >> (32 - r));
}
__host__ __device__ __forceinline__ void threefry2x32(uint32_t k0, uint32_t k1,
                                                      uint32_t& x0, uint32_t& x1) {
    uint32_t k2 = k0 ^ k1 ^ 0x1BD11BDAu;
    x0 += k0; x1 += k1;
#define TF_R(r) { x0 += x1; x1 = rotl32(x1, (r)); x1 ^= x0; }
    TF_R(13) TF_R(15) TF_R(26) TF_R(6)   x0 += k1; x1 += k2 + 1u;
    TF_R(17) TF_R(29) TF_R(16) TF_R(24)  x0 += k2; x1 += k0 + 2u;
    TF_R(13) TF_R(15) TF_R(26) TF_R(6)   x0 += k0; x1 += k1 + 3u;
    TF_R(17) TF_R(29) TF_R(16) TF_R(24)  x0 += k1; x1 += k2 + 4u;
    TF_R(13) TF_R(15) TF_R(26) TF_R(6)   x0 += k2; x1 += k0 + 5u;
#undef TF_R
}

// JAX threefry_partitionable random_bits (default since jax 0.4.36):
// element with 64-bit flat index i (hi=0 here) -> block E(key; 0, i),
// 32-bit output = out0 ^ out1.
__device__ __forceinline__ uint32_t tf_bits(uint32_t k0, uint32_t k1, uint32_t cnt) {
    uint32_t x0 = 0u, x1 = cnt;
    threefry2x32(k0, k1, x0, x1);
    return x0 ^ x1;
}

// uniform(-0.99999994, 1) -> sqrt(2)*erfinv (XLA/Giles f32 polynomial)
__device__ __forceinline__ float bits_to_normal(uint32_t bits) {
    const float LO = -0.99999994f;                     // nextafter(-1, 0)
    float f = __uint_as_float((bits >> 9) | 0x3f800000u) - 1.0f;  // [0,1)
    float u = fmaxf(LO, fmaf(f, 2.0f, LO));            // maxval-minval folds to 2.0f
    float w = -__logf(fmaf(-u, u, 1.0f));              // -log(1-u^2)
    float p;
    if (w < 5.0f) {
        w -= 2.5f;
        p = 2.81022636e-08f;
        p = fmaf(p, w, 3.43273939e-07f);
        p = fmaf(p, w, -3.5233877e-06f);
        p = fmaf(p, w, -4.39150654e-06f);
        p = fmaf(p, w, 0.00021858087f);
        p = fmaf(p, w, -0.00125372503f);
        p = fmaf(p, w, -0.00417768164f);
        p = fmaf(p, w, 0.246640727f);
        p = fmaf(p, w, 1.50140941f);
    } else {
        w = __fsqrt_rn(w) - 3.0f;
        p = -0.000200214257f;
        p = fmaf(p, w, 0.000100950558f);
        p = fmaf(p, w, 0.00134934322f);
        p = fmaf(p, w, -0.00367342844f);
        p = fmaf(p, w, 0.00573950773f);
        p = fmaf(p, w, -0.0076224613f);
        p = fmaf(p, w, 0.00943887047f);
        p = fmaf(p, w, 1.00167406f);
        p = fmaf(p, w, 2.83297682f);
    }
    return 1.41421356f * p * u;
}

// -------- kernel 0: w1_std = exp(0.5*w1_logvar) -----------------------------
__global__ __launch_bounds__(256) void k_w1std(const float* __restrict__ w1_logvar,
                                               float* __restrict__ w1_std) {
    int i = blockIdx.x * 256 + threadIdx.x;
    if (i < HID * IN) w1_std[i] = __expf(0.5f * w1_logvar[i]);
}

// -------- kernel 1: fused eps_w1/eps_b1 + layer-1 matvec + relu -------------
// Thread = (b_pair, o): handles batches b and b+512 (shares the weight row).
__global__ __launch_bounds__(256) void k_layer1(
    const float* __restrict__ x, const float* __restrict__ w1_mu,
    const float* __restrict__ w1_std, const float* __restrict__ b1_mu,
    const float* __restrict__ b1_logvar, float* __restrict__ h,
    uint32_t kw0, uint32_t kw1, uint32_t kb0, uint32_t kb1)
{
    __shared__ float xs0[IN], xs1[IN];
    const int b = blockIdx.y;
    const int o = blockIdx.x * 256 + threadIdx.x;
    const int t = threadIdx.x;                 // 256 == IN
    xs0[t] = x[b * IN + t];
    xs1[t] = x[(b + 512) * IN + t];
    __syncthreads();

    const uint32_t base = (uint32_t)(b * HID + o) * IN;
    const float4* wm4 = (const float4*)(w1_mu  + o * IN);
    const float4* ws4 = (const float4*)(w1_std + o * IN);
    const float4* x04 = (const float4*)xs0;
    const float4* x14 = (const float4*)xs1;

    float acc0 = 0.f, acc1 = 0.f;
    for (int i4 = 0; i4 < IN / 4; ++i4) {
        float4 m4 = wm4[i4], s4 = ws4[i4], xa = x04[i4], xb = x14[i4];
        const float* m = &m4.x; const float* s = &s4.x;
        const float* pa = &xa.x; const float* pb = &xb.x;
        #pragma unroll
        for (int k = 0; k < 4; ++k) {
            uint32_t c = base + (uint32_t)(i4 * 4 + k);
            float e0 = bits_to_normal(tf_bits(kw0, kw1, c));
            float e1 = bits_to_normal(tf_bits(kw0, kw1, c + HALF_W1));
            acc0 = fmaf(fmaf(s[k], e0, m[k]), pa[k], acc0);
            acc1 = fmaf(fmaf(s[k], e1, m[k]), pb[k], acc1);
        }
    }
    // bias: b1_mu + b1_std * eps_b1
    uint32_t cb = (uint32_t)(b * HID + o);
    float eb0 = bits_to_normal(tf_bits(kb0, kb1, cb));
    float eb1 = bits_to_normal(tf_bits(kb0, kb1, cb + HALF_B1));
    float bstd = __expf(0.5f * b1_logvar[o]);
    float bm = b1_mu[o];
    float h0 = acc0 + fmaf(bstd, eb0, bm);
    float h1 = acc1 + fmaf(bstd, eb1, bm);
    h[b * HID + o]         = fmaxf(h0, 0.f);
    h[(b + 512) * HID + o] = fmaxf(h1, 0.f);
}

// -------- kernel 2: fused eps_w2/eps_b2 + layer-2 + mean/var epilogue -------
// ONE wave per (b_pair in [0,512), j in {0,1}) = 1024 waves = 256 blocks.
__global__ __launch_bounds__(256) void k_layer2(
    const float* __restrict__ h, const float* __restrict__ w2_mu,
    const float* __restrict__ w2_logvar, const float* __restrict__ b2_mu,
    const float* __restrict__ b2_logvar, float* __restrict__ out,
    uint32_t kw0, uint32_t kw1, uint32_t kb0, uint32_t kb1)
{
    const int wave = (blockIdx.x * 256 + threadIdx.x) >> 6;  // 0..1023
    const int lane = threadIdx.x & 63;
    const int b = wave >> 1, j = wave & 1;                   // b in [0,512)

    float acc0 = 0.f, acc1 = 0.f;
    #pragma unroll
    for (int oi = 0; oi < HID / 64; ++oi) {
        int o = oi * 64 + lane;
        uint32_t c = (uint32_t)((b * OUT + j) * HID + o);
        float e0 = bits_to_normal(tf_bits(kw0, kw1, c));
        float e1 = bits_to_normal(tf_bits(kw0, kw1, c + HALF_W2));
        float m = w2_mu[j * HID + o];
        float s = __expf(0.5f * w2_logvar[j * HID + o]);
        acc0 = fmaf(fmaf(s, e0, m), h[b * HID + o], acc0);
        acc1 = fmaf(fmaf(s, e1, m), h[(b + 512) * HID + o], acc1);
    }
    #pragma unroll
    for (int off = 32; off > 0; off >>= 1) {
        acc0 += __shfl_down(acc0, off, 64);
        acc1 += __shfl_down(acc1, off, 64);
    }
    if (lane == 0) {
        uint32_t cb = (uint32_t)(b * OUT + j);
        float eb0 = bits_to_normal(tf_bits(kb0, kb1, cb));
        float eb1 = bits_to_normal(tf_bits(kb0, kb1, cb + HALF_B2));
        float bstd = __expf(0.5f * b2_logvar[j]);
        float bm = b2_mu[j];
        float o0 = acc0 + fmaf(bstd, eb0, bm);
        float o1 = acc1 + fmaf(bstd, eb1, bm);
        if (j == 0) {               // mean = out[:,0]
            out[b] = o0;
            out[b + 512] = o1;
        } else {                    // var = max(exp(out[:,1]), 1e-6)
            out[1024 + b]       = fmaxf(__expf(o0), 1e-6f);
            out[1024 + b + 512] = fmaxf(__expf(o1), 1e-6f);
        }
    }
}

extern "C" void kernel_launch(void* const* d_in, const int* in_sizes, int n_in,
                              void* d_out, int out_size, void* d_ws, size_t ws_size,
                              hipStream_t stream) {
    (void)in_sizes; (void)n_in; (void)out_size; (void)ws_size;
    const float* x         = (const float*)d_in[0];
    const float* w1_mu     = (const float*)d_in[1];
    const float* w1_logvar = (const float*)d_in[2];
    const float* b1_mu     = (const float*)d_in[3];
    const float* b1_logvar = (const float*)d_in[4];
    const float* w2_mu     = (const float*)d_in[5];
    const float* w2_logvar = (const float*)d_in[6];
    const float* b2_mu     = (const float*)d_in[7];
    const float* b2_logvar = (const float*)d_in[8];
    float* out = (float*)d_out;

    float* ws_w1std = (float*)d_ws;                 // HID*IN floats
    float* ws_h     = (float*)d_ws + HID * IN;      // BATCH*HID floats

    // nk = split(key(42), 4), PARTITIONABLE (fold-like, jax>=0.4.36 default):
    // nk[i] = threefry2x32((0,42); x0=0, x1=i) -> (out0, out1).
    uint32_t nk[4][2];
    for (uint32_t i = 0; i < 4; ++i) {
        uint32_t a = 0u, c = i;
        threefry2x32(0u, 42u, a, c);
        nk[i][0] = a; nk[i][1] = c;
    }
    const uint32_t kw1a = nk[0][0], kw1b = nk[0][1];   // nk[0] -> eps_w1
    const uint32_t kb1a = nk[1][0], kb1b = nk[1][1];   // nk[1] -> eps_b1
    const uint32_t kw2a = nk[2][0], kw2b = nk[2][1];   // nk[2] -> eps_w2
    const uint32_t kb2a = nk[3][0], kb2b = nk[3][1];   // nk[3] -> eps_b2

    k_w1std<<<(HID * IN + 255) / 256, 256, 0, stream>>>(w1_logvar, ws_w1std);
    k_layer1<<<dim3(2, 512), 256, 0, stream>>>(x, w1_mu, ws_w1std, b1_mu, b1_logvar,
                                               ws_h, kw1a, kw1b, kb1a, kb1b);
    k_layer2<<<256, 256, 0, stream>>>(ws_h, w2_mu, w2_logvar, b2_mu, b2_logvar,
                                      out, kw2a, kw2b, kb2a, kb2b);
}